// Round 11
// baseline (4137.881 us; speedup 1.0000x reference)
//
#include <hip/hip_runtime.h>
#include <hip/hip_bf16.h>

#define HDIM 512
#define BATCH 256
#define NSEQ 144

typedef __attribute__((ext_vector_type(8))) short short8;
typedef __attribute__((ext_vector_type(4))) float f32x4;
typedef __attribute__((ext_vector_type(4))) int int4v;

__device__ __forceinline__ float fast_sigmoid(float x) { return 1.0f / (1.0f + __expf(-x)); }
__device__ __forceinline__ float fast_tanh(float x) {
    x = fminf(fmaxf(x, -12.0f), 12.0f);
    float e = __expf(2.0f * x);
    return (e - 1.0f) / (e + 1.0f);
}
__device__ __forceinline__ short f2bf(float v) {
    __hip_bfloat16 b = __float2bfloat16(v);
    return *reinterpret_cast<short*>(&b);
}
__device__ __forceinline__ float bf2f(short s) {
    __hip_bfloat16 b = *reinterpret_cast<__hip_bfloat16*>(&s);
    return __bfloat162float(b);
}

// Agent scope (sc1) = LLC coherence point — the ONLY working cross-CU sync
// scope on gfx950 (sc0 livelocked in R9/R10). No wbl2/inv anywhere.
__device__ __forceinline__ void agent_load8(short8& d, const short* p) {
    asm volatile("global_load_dwordx4 %0, %1, off sc1" : "=v"(d) : "v"(p));
}
__device__ __forceinline__ void plain_load8(short8& d, const short* p) {
    asm volatile("global_load_dwordx4 %0, %1, off" : "=v"(d) : "v"(p));
}
__device__ __forceinline__ void agent_store16(short* p, int4v v) {
    asm volatile("global_store_dwordx4 %0, %1, off sc1" :: "v"(p), "v"(v) : "memory");
}

// Split fp32 -> (hi, lo) bf16 planes. n4 = n/4.
__global__ __launch_bounds__(256)
void xconv_kernel(const float* __restrict__ src, short* __restrict__ hi,
                  short* __restrict__ lo, int n4)
{
    int i = blockIdx.x * 256 + threadIdx.x;
    if (i >= n4) return;
    float4 v = reinterpret_cast<const float4*>(src)[i];
    float vv[4] = {v.x, v.y, v.z, v.w};
    short oh[4], ol[4];
#pragma unroll
    for (int e = 0; e < 4; ++e) {
        short h = f2bf(vv[e]);
        oh[e] = h;
        ol[e] = f2bf(vv[e] - bf2f(h));
    }
    reinterpret_cast<short4*>(hi)[i] = *reinterpret_cast<const short4*>(oh);
    reinterpret_cast<short4*>(lo)[i] = *reinterpret_cast<const short4*>(ol);
}

// Permuted split weights (VERBATIM R8), j' = 4*u + gate (i,f,g,o), per row:
//   region0: hi([Wih|Whh]) R0S ksteps; region1: hi(Wih) x-only 2 ksteps (0-pad);
//   region2: lo([Wih|Whh]) R0S ksteps.  Z pairing: (xhi|hhi), (xlo), (xhi|hhi).
// h-lo term dropped (validated R8: absmax 9.8e-4).
template<int I>
__global__ __launch_bounds__(256)
void wprep_kernel(const float* __restrict__ Wih, const float* __restrict__ Whh,
                  const float* __restrict__ bih, const float* __restrict__ bhh,
                  short* __restrict__ Wcat, float* __restrict__ bc)
{
    constexpr int R0S = (I + 512) / 32;
    constexpr int NKS = 2 * R0S + 2;
    constexpr int KTOT = NKS * 32;
    constexpr int GR = NKS * 4;           // granules per row (152 / 144)
    const int jp = blockIdx.x;            // 0..2047
    const int u = jp >> 2, g = jp & 3;
    const int srow = g * HDIM + u;
    const int t = threadIdx.x;
    if (t == 255) bc[jp] = bih[srow] + bhh[srow];
    if (t >= GR) return;
    int region, kr;
    if (t < R0S * 4)          { region = 0; kr = t * 8; }
    else if (t < R0S * 4 + 8) { region = 1; kr = (t - R0S * 4) * 8; }
    else                      { region = 2; kr = (t - R0S * 4 - 8) * 8; }
    short o[8];
#pragma unroll
    for (int e = 0; e < 8; ++e) {
        int k = kr + e;
        if (region == 1) {
            o[e] = (k < I) ? f2bf(Wih[(size_t)srow * I + k]) : (short)0;
        } else {
            float s = (k < I) ? Wih[(size_t)srow * I + k]
                              : Whh[(size_t)srow * HDIM + (k - I)];
            short hi = f2bf(s);
            o[e] = (region == 2) ? f2bf(s - bf2f(hi)) : hi;
        }
    }
    *reinterpret_cast<int4*>(Wcat + (size_t)jp * KTOT + t * 8) =
        *reinterpret_cast<const int4*>(o);
}

struct PArgs {
    const short *xdhi, *xdlo, *xfhi, *xflo, *xffhi, *xfflo;
    const short *Wc0, *Wc1, *Wc2;
    const float *bc0, *bc1, *bc2;
    const float *headW;
    short *h0hi, *h1hi;
    float *parts;
    unsigned *flags;      // [bm:4][set:4][bn:64] monotonic step flags
};

// One LSTM step for ONE WAVE (= one independent 16-row recurrence set).
// No __syncthreads anywhere: waves self-stagger so one wave's LLC sync chain
// hides under the other waves' compute. All ordering is per-wave vmcnt.
template<int I>
__device__ __forceinline__ void wave_step(
    const short* __restrict__ Wl, float (&creg)[2][4], float* __restrict__ hsl,
    const float* __restrict__ bcl, const float* __restrict__ hwl,
    const short* __restrict__ xhi, const short* __restrict__ xlo,
    int T, int tloc,
    const short* __restrict__ hhi, short* __restrict__ hohi,
    unsigned* __restrict__ gf,
    float* __restrict__ parts, int seq_t, bool head,
    int bm, int bn, int w, int lane, int s)
{
    constexpr int XF = I / 32;
    constexpr int R0S = XF + 16;
    constexpr int KTOT = (2 * R0S + 2) * 32;
    const int l15 = lane & 15, lg = lane >> 4, gs = l15 & 3;
    const int brow = bm * 64 + w * 16 + l15;
    const int lg8 = lg * 8;

    // x loads first (hide under the flag poll, which drains vmcnt anyway)
    short8 aphi[R0S], axlo[2];
    {
        const short* xbh = xhi + ((size_t)brow * T + tloc) * I + lg8;
        const short* xbl = xlo + ((size_t)brow * T + tloc) * I + lg8;
#pragma unroll
        for (int f = 0; f < XF; ++f) plain_load8(aphi[f], xbh + f * 32);
        plain_load8(axlo[0], xbl);
        if constexpr (XF == 2) plain_load8(axlo[1], xbl + 32);
        else                   axlo[1] = short8{0,0,0,0,0,0,0,0};
    }

    // poll this set's 64 producer flags >= s (64 lanes, one 256B sweep)
    {
        const unsigned* fp = gf + lane;
        unsigned v;
        do {
            asm volatile("global_load_dword %0, %1, off sc1\n\ts_waitcnt vmcnt(0)"
                         : "=v"(v) : "v"(fp));
        } while (__ballot(v < (unsigned)s));
    }
    __builtin_amdgcn_sched_barrier(0);    // rule #18: nothing hoists above the wait

    // h loads (sc1: producer stores are at LLC per flag protocol)
    {
        const short* hb = hhi + ((size_t)brow << 9) + lg8;
#pragma unroll
        for (int f = 0; f < 16; ++f) agent_load8(aphi[XF + f], hb + f * 32);
    }

    f32x4 acc0 = {0.f,0.f,0.f,0.f}, acc1 = {0.f,0.f,0.f,0.f};
    const short* wb0 = Wl + l15 * KTOT;
    const short* wb1 = Wl + (16 + l15) * KTOT;
    const int x0 = l15 & 7, x1 = (16 + l15) & 7;

    auto BMFMA = [&](int ks, short8 aa) {
        int g = ks * 4 + lg;
        short8 b0 = *reinterpret_cast<const short8*>(wb0 + ((g ^ x0) << 3));
        short8 b1 = *reinterpret_cast<const short8*>(wb1 + ((g ^ x1) << 3));
        acc0 = __builtin_amdgcn_mfma_f32_16x16x32_bf16(aa, b0, acc0, 0, 0, 0);
        acc1 = __builtin_amdgcn_mfma_f32_16x16x32_bf16(aa, b1, acc1, 0, 0, 0);
    };

    // x MFMAs (x regs already drained by the poll's vmcnt(0))
#pragma unroll
    for (int f = 0; f < XF; ++f) BMFMA(f, aphi[f]);            // r0 x
    BMFMA(R0S, axlo[0]);                                       // r1
    BMFMA(R0S + 1, axlo[1]);
#pragma unroll
    for (int f = 0; f < XF; ++f) BMFMA(R0S + 2 + f, aphi[f]);  // r2 x
    asm volatile("s_waitcnt vmcnt(0)" ::: "memory");    // h ready
    __builtin_amdgcn_sched_barrier(0);
#pragma unroll
    for (int f = 0; f < 16; ++f) BMFMA(XF + f, aphi[XF + f]);            // r0 h
#pragma unroll
    for (int f = 0; f < 16; ++f) BMFMA(R0S + 2 + XF + f, aphi[XF + f]);  // r2 h

    // Epilogue: D row = lg*4+r (batch), col = l15 -> j'; 4-lane groups = i,f,g,o.
    // c lives in registers (all 4 gs-lanes carry identical copies).
    float hp[4] = {0.f, 0.f, 0.f, 0.f};
#pragma unroll
    for (int nf = 0; nf < 2; ++nf) {
        float bias = bcl[nf * 16 + l15];
        int ul = nf * 4 + (l15 >> 2);
#pragma unroll
        for (int r = 0; r < 4; ++r) {
            float v = (nf ? acc1[r] : acc0[r]) + bias;
            float act = (gs == 2) ? fast_tanh(v) : fast_sigmoid(v);
            int base = lane & ~3;
            float ai = __shfl(act, base,     64);
            float af = __shfl(act, base | 1, 64);
            float ag = __shfl(act, base | 2, 64);
            float ao = __shfl(act, base | 3, 64);
            float cn = af * creg[nf][r] + ai * ag;
            creg[nf][r] = cn;
            float hn = ao * fast_tanh(cn);
            if (gs == 0) hsl[(lg * 4 + r) * 8 + ul] = hn;
            if (head) {
                float p = (gs == 0) ? hn * hwl[ul] : 0.f;
                p += __shfl_xor(p, 4, 64);
                p += __shfl_xor(p, 8, 64);
                hp[r] += p;
            }
        }
    }
    if (head && l15 == 0) {
#pragma unroll
        for (int r = 0; r < 4; ++r) {
            int bg = bm * 64 + w * 16 + lg * 4 + r;
            parts[((size_t)bg * NSEQ + seq_t) * 64 + bn] = hp[r];
        }
    }

    // h out: 16 lanes, one row each (intra-wave LDS handoff; lockstep-safe)
    if (lane < 16) {
        short oh[8];
#pragma unroll
        for (int e = 0; e < 8; ++e) oh[e] = f2bf(hsl[lane * 8 + e]);
        size_t off = ((size_t)(bm * 64 + w * 16 + lane) << 9) + bn * 8;
        agent_store16(hohi + off, *reinterpret_cast<const int4v*>(oh));
    }
    asm volatile("s_waitcnt vmcnt(0)" ::: "memory");    // h at LLC before flag
    if (lane == 0) {
        unsigned tgt = (unsigned)(s + 1);
        asm volatile("global_store_dword %0, %1, off sc1"
                     :: "v"(gf + bn), "v"(tgt) : "memory");
    }
}

__global__ __launch_bounds__(256, 1)
void lstm_persist(PArgs a)
{
    __shared__ short Wl[32 * 1216];       // 77824 B (enc KTOT; dec fits)
    __shared__ float hsl[4][128];         // per-wave h staging slices
    __shared__ float bcl[32];
    __shared__ float hwl[8];

    const int tid = threadIdx.x;
    const int bn = blockIdx.x & 63;       // gate slice: 32 cols
    const int bm = blockIdx.x >> 6;       // row group: 64 rows
    const int w = tid >> 6;               // wave = independent 16-row set
    const int lane = tid & 63;
    unsigned* gf = a.flags + (bm * 4 + w) * 64;

    if (tid < 8) hwl[tid] = a.headW[bn * 8 + tid];   // ordered by s==0 barrier
    float creg[2][4] = {{0.f,0.f,0.f,0.f},{0.f,0.f,0.f,0.f}};

    for (int s = 0; s < 480; ++s) {
        const short *xhi, *xlo, *Wc;
        const float* bc;
        int T, tloc, I_;
        if (s < 336) {
            xhi = a.xdhi; xlo = a.xdlo; Wc = a.Wc0; bc = a.bc0;
            T = 336; tloc = s; I_ = 64;
        } else if (s < 432) {
            xhi = a.xfhi; xlo = a.xflo; Wc = a.Wc1; bc = a.bc1;
            T = 96; tloc = s - 336; I_ = 32;
        } else {
            xhi = a.xffhi; xlo = a.xfflo; Wc = a.Wc2; bc = a.bc2;
            T = 48; tloc = s - 432; I_ = 32;
        }
        if (s == 0 || s == 336 || s == 432) {
            // the ONLY block-level syncs: all waves have finished the prior
            // stage (their flags are stored before reaching this barrier)
            const int KT  = (I_ == 64) ? 1216 : 1152;
            const int GR8 = (I_ == 64) ? 19 : 18;
            __syncthreads();
            int row = tid >> 3, g0 = tid & 7;
            const short* src = Wc + (size_t)(bn * 32 + row) * KT;
            for (int i2 = 0; i2 < GR8; ++i2) {
                int g = g0 + i2 * 8;
                *reinterpret_cast<int4*>(Wl + row * KT + ((g ^ (row & 7)) << 3)) =
                    *reinterpret_cast<const int4*>(src + g * 8);
            }
            if (tid < 32) bcl[tid] = bc[bn * 32 + tid];
            __syncthreads();
        }
        const int par = s & 1;
        const short* hhi = par ? a.h1hi : a.h0hi;
        short* hohi = par ? a.h0hi : a.h1hi;
        bool head = s >= 336;
        int seq_t = s - 336;
        if (I_ == 64)
            wave_step<64>(Wl, creg, hsl[w], bcl, hwl, xhi, xlo, T, tloc,
                          hhi, hohi, gf, a.parts, seq_t, head, bm, bn, w, lane, s);
        else
            wave_step<32>(Wl, creg, hsl[w], bcl, hwl, xhi, xlo, T, tloc,
                          hhi, hohi, gf, a.parts, seq_t, head, bm, bn, w, lane, s);
    }
}

__global__ __launch_bounds__(256)
void head_finish_kernel(const float* __restrict__ partials,
                        const float* __restrict__ head_b,
                        float* __restrict__ out)
{
    int idx = blockIdx.x * 256 + threadIdx.x;   // b*144 + t
    if (idx >= BATCH * NSEQ) return;
    const float* p = partials + (size_t)idx * 64;
    float s = head_b[0];
#pragma unroll
    for (int i = 0; i < 64; ++i) s += p[i];
    out[idx] = s;
}

extern "C" void kernel_launch(void* const* d_in, const int* in_sizes, int n_in,
                              void* d_out, int out_size, void* d_ws, size_t ws_size,
                              hipStream_t stream) {
    const float* x_d      = (const float*)d_in[0];
    const float* x_f      = (const float*)d_in[1];
    const float* x_ff     = (const float*)d_in[2];
    const float* enc_Wih  = (const float*)d_in[3];
    const float* enc_Whh  = (const float*)d_in[4];
    const float* enc_bih  = (const float*)d_in[5];
    const float* enc_bhh  = (const float*)d_in[6];
    const float* decf_Wih = (const float*)d_in[7];
    const float* decf_Whh = (const float*)d_in[8];
    const float* decf_bih = (const float*)d_in[9];
    const float* decf_bhh = (const float*)d_in[10];
    const float* decff_Wih = (const float*)d_in[11];
    const float* decff_Whh = (const float*)d_in[12];
    const float* decff_bih = (const float*)d_in[13];
    const float* decff_bhh = (const float*)d_in[14];
    const float* head_W   = (const float*)d_in[15];
    const float* head_b   = (const float*)d_in[16];
    float* out = (float*)d_out;

    char* base = (char*)d_ws;
    short* h0hi  = (short*)(base + 0);              //   262144 B
    short* h1hi  = (short*)(base + 262144);         //   262144
    unsigned* flags = (unsigned*)(base + 524288);   //     4096 (16 sets x 64)
    float* parts = (float*)(base + 528384);         //  9437184
    float* bcomb = (float*)(base + 9965568);        //    24576
    short* Wcat  = (short*)(base + 9990144);        //  4980736 (enc 2048x1216x2B)
    short* Wc1   = (short*)(base + 14970880);       //  4718592 (dec 2048x1152x2B)
    short* Wc2   = (short*)(base + 19689472);       //  4718592
    short* xdhi  = (short*)(base + 24408064);       // 11010048
    short* xdlo  = (short*)(base + 35418112);       // 11010048
    short* xfhi  = (short*)(base + 46428160);       //  1572864
    short* xflo  = (short*)(base + 48001024);       //  1572864
    short* xffhi = (short*)(base + 49573888);       //   786432
    short* xfflo = (short*)(base + 50360320);       //   786432

    // zero h0, h1, flags
    hipMemsetAsync(base, 0, 528384, stream);

    // input split-precision conversion
    xconv_kernel<<<dim3(5376), dim3(256), 0, stream>>>(x_d,  xdhi,  xdlo,  1376256);
    xconv_kernel<<<dim3(768),  dim3(256), 0, stream>>>(x_f,  xfhi,  xflo,  196608);
    xconv_kernel<<<dim3(384),  dim3(256), 0, stream>>>(x_ff, xffhi, xfflo, 98304);

    // weight prep
    wprep_kernel<64><<<dim3(2048), dim3(256), 0, stream>>>(
        enc_Wih, enc_Whh, enc_bih, enc_bhh, Wcat, bcomb);
    wprep_kernel<32><<<dim3(2048), dim3(256), 0, stream>>>(
        decf_Wih, decf_Whh, decf_bih, decf_bhh, Wc1, bcomb + 2048);
    wprep_kernel<32><<<dim3(2048), dim3(256), 0, stream>>>(
        decff_Wih, decff_Whh, decff_bih, decff_bhh, Wc2, bcomb + 4096);

    // persistent recurrence (one dispatch for all 480 steps)
    PArgs pa;
    pa.xdhi = xdhi; pa.xdlo = xdlo; pa.xfhi = xfhi; pa.xflo = xflo;
    pa.xffhi = xffhi; pa.xfflo = xfflo;
    pa.Wc0 = Wcat; pa.Wc1 = Wc1; pa.Wc2 = Wc2;
    pa.bc0 = bcomb; pa.bc1 = bcomb + 2048; pa.bc2 = bcomb + 4096;
    pa.headW = head_W;
    pa.h0hi = h0hi; pa.h1hi = h1hi;
    pa.parts = parts;
    pa.flags = flags;
    void* kargs[] = { &pa };
    hipError_t ce = hipLaunchCooperativeKernel((const void*)lstm_persist,
                                               dim3(256), dim3(256), kargs,
                                               0, stream);
    if (ce != hipSuccess) {
        lstm_persist<<<dim3(256), dim3(256), 0, stream>>>(pa);
    }

    head_finish_kernel<<<dim3((BATCH * NSEQ + 255) / 256), dim3(256), 0, stream>>>(
        parts, head_b, out);
}